// Round 4
// baseline (253.061 us; speedup 1.0000x reference)
//
#include <hip/hip_runtime.h>
#include <math.h>

// Problem constants
#define BB 16
#define NN 1024
#define DD 512
#define KK 8
#define EPS_ 1e-8f
#define LN_EPS_ 1e-5f
// -0.5 * D * log(2*pi)
#define GLL_C0 (-470.4965290007924f)

typedef __attribute__((ext_vector_type(8))) short short8;
typedef __attribute__((ext_vector_type(4))) short short4v;
typedef __attribute__((ext_vector_type(4))) float f32x4;

// round-to-nearest-even f32 -> bf16 (as short)
static __device__ inline short f2bf(float f) {
    unsigned u = __builtin_bit_cast(unsigned, f);
    u = (u + 0x7fff + ((u >> 16) & 1)) >> 16;
    return (short)u;
}
static __device__ inline float bf2f(short s) {
    unsigned u = ((unsigned)(unsigned short)s) << 16;
    return __builtin_bit_cast(float, u);
}

static __device__ inline void gload16(const void* g, void* l) {
    __builtin_amdgcn_global_load_lds(
        (const __attribute__((address_space(1))) void*)g,
        (__attribute__((address_space(3))) void*)l, 16, 0, 0);
}

// ---------------------------------------------------------------------------
// 1) Fused preprocessing: LN+bf16 cast (blocks 0..4095), weight transpose
//    (4096..4863), slot init (4864..4991).  One dispatch instead of three.
// ---------------------------------------------------------------------------
__global__ __launch_bounds__(256) void pre_kernel(
    const float* __restrict__ emb, const float* __restrict__ lng,
    const float* __restrict__ lnb, short* __restrict__ Abf,
    const float* __restrict__ Wk, const float* __restrict__ Wv,
    const float* __restrict__ Wq, short* __restrict__ Wt,
    const float* __restrict__ noise_init, const float* __restrict__ slots_mu,
    const float* __restrict__ slots_logsigma, short* __restrict__ slots_bf)
{
    int bid = blockIdx.x;
    int tid = threadIdx.x;
    if (bid < 4096) {
        // --- LayerNorm + cast ---
        int row  = bid * 4 + (tid >> 6);
        int lane = tid & 63;
        const float* e = emb + (size_t)row * DD + lane * 8;
        float4 v0 = *(const float4*)e;
        float4 v1 = *(const float4*)(e + 4);
        float v[8] = {v0.x, v0.y, v0.z, v0.w, v1.x, v1.y, v1.z, v1.w};
        float s = 0.0f;
#pragma unroll
        for (int j = 0; j < 8; j++) s += v[j];
#pragma unroll
        for (int off = 32; off; off >>= 1) s += __shfl_xor(s, off);
        float m = s * (1.0f / DD);
        float vs = 0.0f;
#pragma unroll
        for (int j = 0; j < 8; j++) { float d = v[j] - m; vs = fmaf(d, d, vs); }
#pragma unroll
        for (int off = 32; off; off >>= 1) vs += __shfl_xor(vs, off);
        float rstd = rsqrtf(vs * (1.0f / DD) + LN_EPS_);

        float4 g0 = *(const float4*)&lng[lane * 8];
        float4 g1 = *(const float4*)&lng[lane * 8 + 4];
        float4 b0 = *(const float4*)&lnb[lane * 8];
        float4 b1 = *(const float4*)&lnb[lane * 8 + 4];
        float g[8] = {g0.x, g0.y, g0.z, g0.w, g1.x, g1.y, g1.z, g1.w};
        float bb[8] = {b0.x, b0.y, b0.z, b0.w, b1.x, b1.y, b1.z, b1.w};
        short8 o;
#pragma unroll
        for (int j = 0; j < 8; j++) o[j] = f2bf(fmaf((v[j] - m) * rstd, g[j], bb[j]));
        *(short8*)&Abf[(size_t)row * DD + lane * 8] = o;
    } else if (bid < 4864) {
        // --- weight transpose + cast ---
        int idx = bid - 4096;
        int z = idx >> 8, rem = idx & 255;
        const float* W = (z == 0) ? Wk : (z == 1) ? Wv : Wq;
        short* T = Wt + (size_t)z * DD * DD;
        int k0 = (rem & 15) * 32, n0 = (rem >> 4) * 32;
        int tx = tid & 31, ty = tid >> 5;
        __shared__ float t[32][33];
#pragma unroll
        for (int p = 0; p < 4; p++)
            t[ty + p * 8][tx] = W[(size_t)(k0 + ty + p * 8) * DD + n0 + tx];
        __syncthreads();
#pragma unroll
        for (int p = 0; p < 4; p++)
            T[(size_t)(n0 + ty + p * 8) * DD + k0 + tx] = f2bf(t[tx][ty + p * 8]);
    } else {
        // --- slot init ---
        int idx = bid - 4864;
        int b = idx >> 3, k = idx & 7;
#pragma unroll
        for (int q = 0; q < 2; q++) {
            int d = tid + q * 256;
            float sg = expf(slots_logsigma[k * DD + d]);
            float sl = fmaf(sg, noise_init[((size_t)(b * KK + k)) * DD + d],
                            slots_mu[k * DD + d]);
            slots_bf[((size_t)(b * KK + k)) * DD + d] = f2bf(sl);
        }
    }
}

// ---------------------------------------------------------------------------
// 2) bf16 MFMA GEMM, 128x128 tile, BK=64, XOR-swizzled LDS (2-way max bank
//    aliasing = free).  grid (4, 129, 2):
//      by<128: z=0 -> keys -> E = [bf16(c^2) | bf16(c)]; z=1 -> Vbf=bf16(c)
//      by==128, z=0: queries = slotbf @ Wq^T + bq (fp32); z=1: idle
// ---------------------------------------------------------------------------
__global__ __launch_bounds__(256) void gemm_mfma_kernel(
    const short* __restrict__ Abf, const short* __restrict__ slotbf,
    const short* __restrict__ Wt,
    const float* __restrict__ bk, const float* __restrict__ bv,
    const float* __restrict__ bq,
    short* __restrict__ E, short* __restrict__ Vbf, float* __restrict__ Cq)
{
    int z = blockIdx.z, by = blockIdx.y;
    const short* A; const short* Bt; const float* bias;
    int qmode = 0, row0 = 0;
    if (by == 128) {
        if (z == 1) return;
        A = slotbf; Bt = Wt + (size_t)2 * DD * DD; bias = bq; qmode = 1;
    } else {
        A = Abf + (size_t)by * 128 * DD;
        Bt = Wt + (size_t)z * DD * DD;
        bias = z ? bv : bk;
        row0 = by * 128;
    }

    __shared__ short As[128 * 64];
    __shared__ short Bs[128 * 64];

    int tid = threadIdx.x;
    int w = tid >> 6, l = tid & 63;
    int col0 = blockIdx.x * 128;

    // staging: lane l covers chunk position p=l&7 of row (base + l>>3);
    // source global chunk g = p ^ (r&7)  (r&7 == l>>3)
    int sr = l >> 3;
    int sg_off = ((l & 7) ^ sr) * 8;

    int mq = (w & 1) * 64, nq = (w >> 1) * 64;
    int fr = l & 15;

    f32x4 acc[4][4] = {};

    for (int k0 = 0; k0 < DD; k0 += 64) {
        __syncthreads();
#pragma unroll
        for (int j = 0; j < 4; j++) {
            int rb = w * 32 + j * 8;          // 8-row group base
            int r  = rb + sr;
            gload16(A  + (size_t)r * DD + k0 + sg_off, &As[rb * 64 + l * 8]);
            gload16(Bt + (size_t)(col0 + r) * DD + k0 + sg_off, &Bs[rb * 64 + l * 8]);
        }
        __syncthreads();

#pragma unroll
        for (int kk = 0; kk < 2; kk++) {
            int g = kk * 4 + (l >> 4);
            short8 af[4], bfv[4];
#pragma unroll
            for (int mi = 0; mi < 4; mi++) {
                int row = mq + mi * 16 + fr;
                af[mi] = *(const short8*)&As[row * 64 + (g ^ (fr & 7)) * 8];
            }
#pragma unroll
            for (int ni = 0; ni < 4; ni++) {
                int row = nq + ni * 16 + fr;
                bfv[ni] = *(const short8*)&Bs[row * 64 + (g ^ (fr & 7)) * 8];
            }
#pragma unroll
            for (int mi = 0; mi < 4; mi++)
#pragma unroll
                for (int ni = 0; ni < 4; ni++)
                    acc[mi][ni] = __builtin_amdgcn_mfma_f32_16x16x32_bf16(
                        af[mi], bfv[ni], acc[mi][ni], 0, 0, 0);
        }
    }

    int orow = (l >> 4) * 4, ocol = l & 15;
#pragma unroll
    for (int ni = 0; ni < 4; ni++) {
        int col = col0 + nq + ni * 16 + ocol;
        float bv_ = bias[col];
#pragma unroll
        for (int mi = 0; mi < 4; mi++) {
#pragma unroll
            for (int r = 0; r < 4; r++) {
                int row = row0 + mq + mi * 16 + orow + r;
                float val = acc[mi][ni][r] + bv_;
                if (qmode) {
                    Cq[(size_t)row * DD + col] = val;
                } else if (z == 0) {
                    E[(size_t)row * 1024 + col]       = f2bf(val * val);
                    E[(size_t)row * 1024 + 512 + col] = f2bf(val);
                } else {
                    Vbf[(size_t)row * DD + col] = f2bf(val);
                }
            }
        }
    }
}

// ---------------------------------------------------------------------------
// 3) fprep0: initial F/off/mix from exp(logsigma) + queries; zero k>=8 rows.
// ---------------------------------------------------------------------------
__global__ __launch_bounds__(256) void fprep0_kernel(
    const float* __restrict__ slots_logsigma, const float* __restrict__ queries,
    const float* __restrict__ mixing_coeffs, short* __restrict__ F_bt,
    float* __restrict__ off, float* __restrict__ mix16, float* __restrict__ colsum)
{
    int b = blockIdx.x, k = blockIdx.y;
    int tid = threadIdx.x;
    short* Fr = F_bt + (size_t)(b * 16 + k) * 1024;
    if (k >= KK) {
        short4v zv = {0, 0, 0, 0};
        *(short4v*)&Fr[tid * 4] = zv;
        if (tid == 0) { off[b * 16 + k] = 0.0f; mix16[b * 16 + k] = 0.0f; }
        return;
    }
    float c = 0.0f, ld = 0.0f;
#pragma unroll
    for (int q = 0; q < 2; q++) {
        int d = tid * 2 + q;
        float sg = expf(slots_logsigma[k * DD + d]);
        float iv = 1.0f / (sg * sg + EPS_);
        float qv = queries[((size_t)(b * KK + k)) * DD + d];
        Fr[d]       = f2bf(-0.5f * iv);
        Fr[512 + d] = f2bf(qv * iv);
        c  = fmaf(qv * qv, iv, c);
        ld += logf(fabsf(sg) + EPS_);
    }
    __shared__ float rc[256], rl[256];
    rc[tid] = c; rl[tid] = ld;
    __syncthreads();
    for (int s = 128; s > 0; s >>= 1) {
        if (tid < s) { rc[tid] += rc[tid + s]; rl[tid] += rl[tid + s]; }
        __syncthreads();
    }
    if (tid == 0) {
        off[b * 16 + k]    = GLL_C0 - 0.5f * rl[0] - 0.5f * rc[0];
        mix16[b * 16 + k]  = mixing_coeffs[k];
        colsum[b * KK + k] = 0.0f;
    }
}

// ---------------------------------------------------------------------------
// 4) gll as batched MFMA GEMM + normalization epilogue + colsum atomics.
// ---------------------------------------------------------------------------
__global__ __launch_bounds__(256) void gll_mfma_kernel(
    const short* __restrict__ E, const short* __restrict__ F_bt,
    const float* __restrict__ off, const float* __restrict__ mix16,
    float* __restrict__ attn, float* __restrict__ colsum)
{
    int b = blockIdx.y;
    int tid = threadIdx.x;
    int w = tid >> 6, l = tid & 63;
    int m0 = blockIdx.x * 64 + w * 16;

    const short* Ea = E + ((size_t)(b * NN + m0 + (l & 15))) * 1024 + (l >> 4) * 8;
    const short* Fa = F_bt + (size_t)(b * 16 + (l & 15)) * 1024 + (l >> 4) * 8;

    f32x4 acc = {};
#pragma unroll 8
    for (int k0 = 0; k0 < 1024; k0 += 32) {
        short8 af = *(const short8*)&Ea[k0];
        short8 bf = *(const short8*)&Fa[k0];
        acc = __builtin_amdgcn_mfma_f32_16x16x32_bf16(af, bf, acc, 0, 0, 0);
    }

    int col = l & 15;
    int rbase = m0 + (l >> 4) * 4;
    float offv = off[b * 16 + col];
    float mixv = mix16[b * 16 + col];

    float a[4], den[4];
#pragma unroll
    for (int r = 0; r < 4; r++) {
        a[r] = mixv * (acc[r] + offv);
        den[r] = a[r];
    }
#pragma unroll
    for (int mask = 1; mask <= 8; mask <<= 1)
#pragma unroll
        for (int r = 0; r < 4; r++) den[r] += __shfl_xor(den[r], mask);

    float csl = 0.0f;
    if (col < KK) {
#pragma unroll
        for (int r = 0; r < 4; r++) {
            float v = a[r] / den[r];
            attn[((size_t)(b * NN + rbase + r)) * KK + col] = v;
            csl += v;
        }
    }
    csl += __shfl_xor(csl, 16);
    csl += __shfl_xor(csl, 32);
    if (l < KK) atomicAdd(&colsum[b * KK + l], csl);
}

// ---------------------------------------------------------------------------
// 5) musigma partials over 128-row chunks: s1 = sum a*v, s2 = sum a*v^2.
//    grid (BB, 8).  bf16 values, 2 d per thread.
// ---------------------------------------------------------------------------
__global__ __launch_bounds__(256) void musigma_kernel(
    const short* __restrict__ Vbf, const float* __restrict__ attn,
    float* __restrict__ s1p, float* __restrict__ s2p)
{
    int b = blockIdx.x, ns = blockIdx.y;
    int tid = threadIdx.x;
    int d0 = tid * 2;
    __shared__ float asml[128 * KK];
    const float* ab = attn + ((size_t)(b * NN + ns * 128)) * KK;
    ((float4*)asml)[tid] = ((const float4*)ab)[tid];
    __syncthreads();

    float s1[2][KK] = {}, s2[2][KK] = {};
    const short* vb = Vbf + ((size_t)(b * NN + ns * 128)) * DD + d0;
#pragma unroll 4
    for (int nn = 0; nn < 128; nn++) {
        short2 vs = *(const short2*)&vb[(size_t)nn * DD];
        float v0 = bf2f(vs.x), v1 = bf2f(vs.y);
        float v0q = v0 * v0, v1q = v1 * v1;
#pragma unroll
        for (int k = 0; k < KK; k++) {
            float a = asml[nn * KK + k];
            s1[0][k] = fmaf(a, v0, s1[0][k]);
            s2[0][k] = fmaf(a, v0q, s2[0][k]);
            s1[1][k] = fmaf(a, v1, s1[1][k]);
            s2[1][k] = fmaf(a, v1q, s2[1][k]);
        }
    }
    size_t base = ((size_t)(b * 8 + ns) * KK) * DD + d0;
#pragma unroll
    for (int k = 0; k < KK; k++) {
        *(float2*)&s1p[base + (size_t)k * DD] = make_float2(s1[0][k], s1[1][k]);
        *(float2*)&s2p[base + (size_t)k * DD] = make_float2(s2[0][k], s2[1][k]);
    }
}

// ---------------------------------------------------------------------------
// 6) fprep_fused: finalize (mu/sigma from partials) + next-iter F/off/mix +
//    colsum reset.  grid (BB, 8).
// ---------------------------------------------------------------------------
__global__ __launch_bounds__(256) void fprep_fused_kernel(
    const float* __restrict__ s1p, const float* __restrict__ s2p,
    const float* __restrict__ queries, float* __restrict__ colsum,
    short* __restrict__ F_bt, float* __restrict__ off, float* __restrict__ mix16)
{
    int b = blockIdx.x, k = blockIdx.y;
    int tid = threadIdx.x;
    float cs   = colsum[b * KK + k];
    float inv  = 1.0f / (cs + EPS_);
    float ssum = cs * inv;
    short* Fr = F_bt + (size_t)(b * 16 + k) * 1024;

    float c = 0.0f, ld = 0.0f;
#pragma unroll
    for (int q = 0; q < 2; q++) {
        int d = tid * 2 + q;
        float s1 = 0.0f, s2 = 0.0f;
#pragma unroll
        for (int ns = 0; ns < 8; ns++) {
            size_t o = ((size_t)(b * 8 + ns) * KK + k) * DD + d;
            s1 += s1p[o];
            s2 += s2p[o];
        }
        float m  = s1 * inv;
        float sg = s2 * inv - m * m * (2.0f - ssum);
        float iv = 1.0f / (sg * sg + EPS_);
        float qv = queries[((size_t)(b * KK + k)) * DD + d];
        Fr[d]       = f2bf(-0.5f * iv);
        Fr[512 + d] = f2bf(qv * iv);
        c  = fmaf(qv * qv, iv, c);
        ld += logf(fabsf(sg) + EPS_);
    }
    __shared__ float rc[256], rl[256];
    rc[tid] = c; rl[tid] = ld;
    __syncthreads();
    for (int s = 128; s > 0; s >>= 1) {
        if (tid < s) { rc[tid] += rc[tid + s]; rl[tid] += rl[tid + s]; }
        __syncthreads();
    }
    if (tid == 0) {
        off[b * 16 + k]    = GLL_C0 - 0.5f * rl[0] - 0.5f * rc[0];
        mix16[b * 16 + k]  = ssum * (1.0f / NN);
        colsum[b * KK + k] = 0.0f;
    }
}

// ---------------------------------------------------------------------------
// 7) Final: finalize last iter (mu/sigma from partials) -> slots out; attn^T.
// ---------------------------------------------------------------------------
__global__ __launch_bounds__(256) void final_kernel(
    const float* __restrict__ s1p, const float* __restrict__ s2p,
    const float* __restrict__ colsum, const float* __restrict__ noise_final,
    const float* __restrict__ attn, float* __restrict__ out)
{
    int gid = blockIdx.x * 256 + threadIdx.x;
    if (gid < BB * KK * DD) {
        int d = gid & 511;
        int k = (gid >> 9) & 7;
        int b = gid >> 12;
        float s1 = 0.0f, s2 = 0.0f;
#pragma unroll
        for (int ns = 0; ns < 8; ns++) {
            size_t o = ((size_t)(b * 8 + ns) * KK + k) * DD + d;
            s1 += s1p[o];
            s2 += s2p[o];
        }
        float cs   = colsum[b * KK + k];
        float inv  = 1.0f / (cs + EPS_);
        float ssum = cs * inv;
        float m    = s1 * inv;
        float sg   = s2 * inv - m * m * (2.0f - ssum);
        out[gid] = fmaf(fmaxf(fabsf(sg), EPS_), noise_final[gid], m);
    }
    if (gid < BB * KK * NN) {
        int b = gid >> 13;
        int k = (gid >> 10) & 7;
        int n = gid & 1023;
        float cs = colsum[b * KK + k];
        out[BB * KK * DD + gid] = attn[((size_t)(b * NN + n)) * KK + k] / (cs + EPS_);
    }
}

// ---------------------------------------------------------------------------
extern "C" void kernel_launch(void* const* d_in, const int* in_sizes, int n_in,
                              void* d_out, int out_size, void* d_ws, size_t ws_size,
                              hipStream_t stream)
{
    const float* emb         = (const float*)d_in[0];
    const float* noise_init  = (const float*)d_in[1];
    const float* noise_final = (const float*)d_in[2];
    const float* slots_mu    = (const float*)d_in[3];
    const float* slots_logsg = (const float*)d_in[4];
    const float* mixing_co   = (const float*)d_in[5];
    const float* Wk          = (const float*)d_in[6];
    const float* bk          = (const float*)d_in[7];
    const float* Wq          = (const float*)d_in[8];
    const float* bq          = (const float*)d_in[9];
    const float* Wv          = (const float*)d_in[10];
    const float* bv          = (const float*)d_in[11];
    const float* ln_g        = (const float*)d_in[12];
    const float* ln_b        = (const float*)d_in[13];
    float* out = (float*)d_out;

    // workspace layout
    float* ws = (float*)d_ws;
    float* queries = ws;                                 // 65536
    float* attn    = queries + BB * KK * DD;             // 131072
    float* s1p     = attn + BB * NN * KK;                // 16*8*8*512 = 524288
    float* s2p     = s1p + (size_t)BB * 8 * KK * DD;     // 524288
    float* off     = s2p + (size_t)BB * 8 * KK * DD;     // 256
    float* mix16   = off + BB * 16;                      // 256
    float* colsum  = mix16 + BB * 16;                    // 128
    short* Abf     = (short*)(colsum + BB * KK);         // 16*1024*512
    short* E       = Abf + (size_t)BB * NN * DD;         // 16*1024*1024
    short* Vbf     = E + (size_t)BB * NN * 1024;         // 16*1024*512
    short* Wt      = Vbf + (size_t)BB * NN * DD;         // 3*512*512
    short* slotbf  = Wt + (size_t)3 * DD * DD;           // 128*512
    short* F_bt    = slotbf + (size_t)BB * KK * DD;      // 16*16*1024

    pre_kernel<<<4992, 256, 0, stream>>>(
        emb, ln_g, ln_b, Abf, Wk, Wv, Wq, Wt,
        noise_init, slots_mu, slots_logsg, slotbf);

    // keys -> E, values -> Vbf, queries -> fp32 (all one dispatch)
    gemm_mfma_kernel<<<dim3(DD / 128, 129, 2), 256, 0, stream>>>(
        Abf, slotbf, Wt, bk, bv, bq, E, Vbf, queries);

    fprep0_kernel<<<dim3(BB, 16), 256, 0, stream>>>(
        slots_logsg, queries, mixing_co, F_bt, off, mix16, colsum);

    for (int it = 0; it < 3; it++) {
        gll_mfma_kernel<<<dim3(16, BB), 256, 0, stream>>>(
            E, F_bt, off, mix16, attn, colsum);
        musigma_kernel<<<dim3(BB, 8), 256, 0, stream>>>(Vbf, attn, s1p, s2p);
        if (it < 2)
            fprep_fused_kernel<<<dim3(BB, KK), 256, 0, stream>>>(
                s1p, s2p, queries, colsum, F_bt, off, mix16);
    }

    final_kernel<<<BB * KK * NN / 256, 256, 0, stream>>>(
        s1p, s2p, colsum, noise_final, attn, out);
}

// Round 5
// 243.790 us; speedup vs baseline: 1.0380x; 1.0380x over previous
//
#include <hip/hip_runtime.h>
#include <math.h>

// Problem constants
#define BB 16
#define NN 1024
#define DD 512
#define KK 8
#define EPS_ 1e-8f
#define LN_EPS_ 1e-5f
// -0.5 * D * log(2*pi)
#define GLL_C0 (-470.4965290007924f)

typedef __attribute__((ext_vector_type(8))) short short8;
typedef __attribute__((ext_vector_type(4))) short short4v;
typedef __attribute__((ext_vector_type(4))) float f32x4;

// round-to-nearest-even f32 -> bf16 (as short)
static __device__ inline short f2bf(float f) {
    unsigned u = __builtin_bit_cast(unsigned, f);
    u = (u + 0x7fff + ((u >> 16) & 1)) >> 16;
    return (short)u;
}
static __device__ inline float bf2f(short s) {
    unsigned u = ((unsigned)(unsigned short)s) << 16;
    return __builtin_bit_cast(float, u);
}

static __device__ inline void gload16(const void* g, void* l) {
    __builtin_amdgcn_global_load_lds(
        (const __attribute__((address_space(1))) void*)g,
        (__attribute__((address_space(3))) void*)l, 16, 0, 0);
}

// ---------------------------------------------------------------------------
// 1) Fused preprocessing: LN+bf16 cast (blocks 0..4095), weight transpose
//    into concat [Wk^T; Wv^T] + WqT (4096..4863), slot init (4864..4991).
// ---------------------------------------------------------------------------
__global__ __launch_bounds__(256) void pre_kernel(
    const float* __restrict__ emb, const float* __restrict__ lng,
    const float* __restrict__ lnb, short* __restrict__ Abf,
    const float* __restrict__ Wk, const float* __restrict__ Wv,
    const float* __restrict__ Wq, short* __restrict__ WtKV, short* __restrict__ WqT,
    const float* __restrict__ noise_init, const float* __restrict__ slots_mu,
    const float* __restrict__ slots_logsigma, short* __restrict__ slots_bf)
{
    int bid = blockIdx.x;
    int tid = threadIdx.x;
    if (bid < 4096) {
        // --- LayerNorm + cast ---
        int row  = bid * 4 + (tid >> 6);
        int lane = tid & 63;
        const float* e = emb + (size_t)row * DD + lane * 8;
        float4 v0 = *(const float4*)e;
        float4 v1 = *(const float4*)(e + 4);
        float v[8] = {v0.x, v0.y, v0.z, v0.w, v1.x, v1.y, v1.z, v1.w};
        float s = 0.0f;
#pragma unroll
        for (int j = 0; j < 8; j++) s += v[j];
#pragma unroll
        for (int off = 32; off; off >>= 1) s += __shfl_xor(s, off);
        float m = s * (1.0f / DD);
        float vs = 0.0f;
#pragma unroll
        for (int j = 0; j < 8; j++) { float d = v[j] - m; vs = fmaf(d, d, vs); }
#pragma unroll
        for (int off = 32; off; off >>= 1) vs += __shfl_xor(vs, off);
        float rstd = rsqrtf(vs * (1.0f / DD) + LN_EPS_);

        float4 g0 = *(const float4*)&lng[lane * 8];
        float4 g1 = *(const float4*)&lng[lane * 8 + 4];
        float4 b0 = *(const float4*)&lnb[lane * 8];
        float4 b1 = *(const float4*)&lnb[lane * 8 + 4];
        float g[8] = {g0.x, g0.y, g0.z, g0.w, g1.x, g1.y, g1.z, g1.w};
        float bb[8] = {b0.x, b0.y, b0.z, b0.w, b1.x, b1.y, b1.z, b1.w};
        short8 o;
#pragma unroll
        for (int j = 0; j < 8; j++) o[j] = f2bf(fmaf((v[j] - m) * rstd, g[j], bb[j]));
        *(short8*)&Abf[(size_t)row * DD + lane * 8] = o;
    } else if (bid < 4864) {
        // --- weight transpose + cast ---
        int idx = bid - 4096;
        int z = idx >> 8, rem = idx & 255;
        const float* W = (z == 0) ? Wk : (z == 1) ? Wv : Wq;
        short* T; int nbase;
        if (z < 2) { T = WtKV; nbase = z * 512; } else { T = WqT; nbase = 0; }
        int k0 = (rem & 15) * 32, n0 = (rem >> 4) * 32;
        int tx = tid & 31, ty = tid >> 5;
        __shared__ float t[32][33];
#pragma unroll
        for (int p = 0; p < 4; p++)
            t[ty + p * 8][tx] = W[(size_t)(k0 + ty + p * 8) * DD + n0 + tx];
        __syncthreads();
#pragma unroll
        for (int p = 0; p < 4; p++)
            T[(size_t)(nbase + n0 + ty + p * 8) * DD + k0 + tx] = f2bf(t[tx][ty + p * 8]);
    } else {
        // --- slot init ---
        int idx = bid - 4864;
        int b = idx >> 3, k = idx & 7;
#pragma unroll
        for (int q = 0; q < 2; q++) {
            int d = tid + q * 256;
            float sg = expf(slots_logsigma[k * DD + d]);
            float sl = fmaf(sg, noise_init[((size_t)(b * KK + k)) * DD + d],
                            slots_mu[k * DD + d]);
            slots_bf[((size_t)(b * KK + k)) * DD + d] = f2bf(sl);
        }
    }
}

// ---------------------------------------------------------------------------
// 2) Merged bf16 MFMA GEMM, 128x128 tile, BK=64, XOR-swizzled LDS.
//    grid (8, 129):
//      y<128: C = A @ WtKV^T (N=1024): col<512 -> E=[bf16(c^2)|bf16(c)] (keys),
//             col>=512 -> Vbf=bf16(c) (values)
//      y==128 && x<4: queries = slotbf @ WqT^T + bq (fp32)
// ---------------------------------------------------------------------------
__global__ __launch_bounds__(256) void gemm_mfma_kernel(
    const short* __restrict__ Abf, const short* __restrict__ slotbf,
    const short* __restrict__ WtKV, const short* __restrict__ WqT,
    const float* __restrict__ bk, const float* __restrict__ bv,
    const float* __restrict__ bq,
    short* __restrict__ E, short* __restrict__ Vbf, float* __restrict__ Cq)
{
    int x = blockIdx.x, by = blockIdx.y;
    const short* A; const short* Bt;
    int qmode = 0, row0 = 0;
    if (by == 128) {
        if (x >= 4) return;
        A = slotbf; Bt = WqT; qmode = 1;
    } else {
        A = Abf + (size_t)by * 128 * DD;
        Bt = WtKV;
        row0 = by * 128;
    }

    __shared__ short As[128 * 64];
    __shared__ short Bs[128 * 64];

    int tid = threadIdx.x;
    int w = tid >> 6, l = tid & 63;
    int col0 = x * 128;

    // staging: lane l covers chunk position p=l&7 of row (base + l>>3);
    // source global chunk g = p ^ (r&7)
    int sr = l >> 3;
    int sg_off = ((l & 7) ^ sr) * 8;

    int mq = (w & 1) * 64, nq = (w >> 1) * 64;
    int fr = l & 15;

    f32x4 acc[4][4] = {};

    for (int k0 = 0; k0 < DD; k0 += 64) {
        __syncthreads();
#pragma unroll
        for (int j = 0; j < 4; j++) {
            int rb = w * 32 + j * 8;          // 8-row group base
            int r  = rb + sr;
            gload16(A  + (size_t)r * DD + k0 + sg_off, &As[rb * 64 + l * 8]);
            gload16(Bt + (size_t)(col0 + r) * DD + k0 + sg_off, &Bs[rb * 64 + l * 8]);
        }
        __syncthreads();

#pragma unroll
        for (int kk = 0; kk < 2; kk++) {
            int g = kk * 4 + (l >> 4);
            short8 af[4], bfv[4];
#pragma unroll
            for (int mi = 0; mi < 4; mi++) {
                int row = mq + mi * 16 + fr;
                af[mi] = *(const short8*)&As[row * 64 + (g ^ (fr & 7)) * 8];
            }
#pragma unroll
            for (int ni = 0; ni < 4; ni++) {
                int row = nq + ni * 16 + fr;
                bfv[ni] = *(const short8*)&Bs[row * 64 + (g ^ (fr & 7)) * 8];
            }
#pragma unroll
            for (int mi = 0; mi < 4; mi++)
#pragma unroll
                for (int ni = 0; ni < 4; ni++)
                    acc[mi][ni] = __builtin_amdgcn_mfma_f32_16x16x32_bf16(
                        af[mi], bfv[ni], acc[mi][ni], 0, 0, 0);
        }
    }

    int orow = (l >> 4) * 4, ocol = l & 15;
#pragma unroll
    for (int ni = 0; ni < 4; ni++) {
        int col = col0 + nq + ni * 16 + ocol;
        float bv_ = qmode ? bq[col] : (col < 512 ? bk[col] : bv[col - 512]);
#pragma unroll
        for (int mi = 0; mi < 4; mi++) {
#pragma unroll
            for (int r = 0; r < 4; r++) {
                int row = row0 + mq + mi * 16 + orow + r;
                float val = acc[mi][ni][r] + bv_;
                if (qmode) {
                    Cq[(size_t)row * DD + col] = val;
                } else if (col < 512) {
                    E[(size_t)row * 1024 + col]       = f2bf(val * val);
                    E[(size_t)row * 1024 + 512 + col] = f2bf(val);
                } else {
                    Vbf[(size_t)row * DD + (col - 512)] = f2bf(val);
                }
            }
        }
    }
}

// ---------------------------------------------------------------------------
// 3) fprep0: initial F/off/mix from exp(logsigma) + queries; zero k>=8 rows.
// ---------------------------------------------------------------------------
__global__ __launch_bounds__(256) void fprep0_kernel(
    const float* __restrict__ slots_logsigma, const float* __restrict__ queries,
    const float* __restrict__ mixing_coeffs, short* __restrict__ F_bt,
    float* __restrict__ off, float* __restrict__ mix16, float* __restrict__ colsum)
{
    int b = blockIdx.x, k = blockIdx.y;
    int tid = threadIdx.x;
    short* Fr = F_bt + (size_t)(b * 16 + k) * 1024;
    if (k >= KK) {
        short4v zv = {0, 0, 0, 0};
        *(short4v*)&Fr[tid * 4] = zv;
        if (tid == 0) { off[b * 16 + k] = 0.0f; mix16[b * 16 + k] = 0.0f; }
        return;
    }
    float c = 0.0f, ld = 0.0f;
#pragma unroll
    for (int q = 0; q < 2; q++) {
        int d = tid * 2 + q;
        float sg = expf(slots_logsigma[k * DD + d]);
        float iv = 1.0f / (sg * sg + EPS_);
        float qv = queries[((size_t)(b * KK + k)) * DD + d];
        Fr[d]       = f2bf(-0.5f * iv);
        Fr[512 + d] = f2bf(qv * iv);
        c  = fmaf(qv * qv, iv, c);
        ld += logf(fabsf(sg) + EPS_);
    }
    __shared__ float rc[256], rl[256];
    rc[tid] = c; rl[tid] = ld;
    __syncthreads();
    for (int s = 128; s > 0; s >>= 1) {
        if (tid < s) { rc[tid] += rc[tid + s]; rl[tid] += rl[tid + s]; }
        __syncthreads();
    }
    if (tid == 0) {
        off[b * 16 + k]    = GLL_C0 - 0.5f * rl[0] - 0.5f * rc[0];
        mix16[b * 16 + k]  = mixing_coeffs[k];
        colsum[b * KK + k] = 0.0f;
    }
}

// ---------------------------------------------------------------------------
// 4) gll MFMA with split-K x4: each of 4 waves does K=256 (8 MFMAs), LDS
//    reduce, wave 0 does the normalization epilogue.  grid (64, BB).
// ---------------------------------------------------------------------------
__global__ __launch_bounds__(256) void gll_mfma_kernel(
    const short* __restrict__ E, const short* __restrict__ F_bt,
    const float* __restrict__ off, const float* __restrict__ mix16,
    float* __restrict__ attn, float* __restrict__ colsum)
{
    int b = blockIdx.y;
    int tid = threadIdx.x;
    int w = tid >> 6, l = tid & 63;
    int m0 = blockIdx.x * 16;

    const short* Ea = E + ((size_t)(b * NN + m0 + (l & 15))) * 1024 + (l >> 4) * 8;
    const short* Fa = F_bt + (size_t)(b * 16 + (l & 15)) * 1024 + (l >> 4) * 8;

    f32x4 acc = {};
    int kbase = w * 256;
#pragma unroll
    for (int j = 0; j < 8; j++) {
        int k0 = kbase + j * 32;
        short8 af = *(const short8*)&Ea[k0];
        short8 bf = *(const short8*)&Fa[k0];
        acc = __builtin_amdgcn_mfma_f32_16x16x32_bf16(af, bf, acc, 0, 0, 0);
    }

    __shared__ f32x4 red[3][64];
    if (w) red[w - 1][l] = acc;
    __syncthreads();
    if (w) return;
#pragma unroll
    for (int i = 0; i < 3; i++) acc += red[i][l];

    int col = l & 15;
    int rbase = m0 + (l >> 4) * 4;
    float offv = off[b * 16 + col];
    float mixv = mix16[b * 16 + col];

    float a[4], den[4];
#pragma unroll
    for (int r = 0; r < 4; r++) {
        a[r] = mixv * (acc[r] + offv);
        den[r] = a[r];
    }
#pragma unroll
    for (int mask = 1; mask <= 8; mask <<= 1)
#pragma unroll
        for (int r = 0; r < 4; r++) den[r] += __shfl_xor(den[r], mask);

    float csl = 0.0f;
    if (col < KK) {
#pragma unroll
        for (int r = 0; r < 4; r++) {
            float v = a[r] / den[r];
            attn[((size_t)(b * NN + rbase + r)) * KK + col] = v;
            csl += v;
        }
    }
    csl += __shfl_xor(csl, 16);
    csl += __shfl_xor(csl, 32);
    if (l < KK) atomicAdd(&colsum[b * KK + l], csl);
}

// ---------------------------------------------------------------------------
// 5) musigma partials over 64-row chunks: s1 = sum a*v, s2 = sum a*v^2.
//    grid (BB, 16).  bf16 values, 2 d per thread.
// ---------------------------------------------------------------------------
__global__ __launch_bounds__(256) void musigma_kernel(
    const short* __restrict__ Vbf, const float* __restrict__ attn,
    float* __restrict__ s1p, float* __restrict__ s2p)
{
    int b = blockIdx.x, ns = blockIdx.y;
    int tid = threadIdx.x;
    int d0 = tid * 2;
    __shared__ float asml[64 * KK];
    const float* ab = attn + ((size_t)(b * NN + ns * 64)) * KK;
    if (tid < 128) ((float4*)asml)[tid] = ((const float4*)ab)[tid];
    __syncthreads();

    float s1[2][KK] = {}, s2[2][KK] = {};
    const short* vb = Vbf + ((size_t)(b * NN + ns * 64)) * DD + d0;
#pragma unroll 4
    for (int nn = 0; nn < 64; nn++) {
        short2 vs = *(const short2*)&vb[(size_t)nn * DD];
        float v0 = bf2f(vs.x), v1 = bf2f(vs.y);
        float v0q = v0 * v0, v1q = v1 * v1;
#pragma unroll
        for (int k = 0; k < KK; k++) {
            float a = asml[nn * KK + k];
            s1[0][k] = fmaf(a, v0, s1[0][k]);
            s2[0][k] = fmaf(a, v0q, s2[0][k]);
            s1[1][k] = fmaf(a, v1, s1[1][k]);
            s2[1][k] = fmaf(a, v1q, s2[1][k]);
        }
    }
    size_t base = ((size_t)(b * 16 + ns) * KK) * DD + d0;
#pragma unroll
    for (int k = 0; k < KK; k++) {
        *(float2*)&s1p[base + (size_t)k * DD] = make_float2(s1[0][k], s1[1][k]);
        *(float2*)&s2p[base + (size_t)k * DD] = make_float2(s2[0][k], s2[1][k]);
    }
}

// ---------------------------------------------------------------------------
// 6) fprep_fused: finalize (mu/sigma from 16 partials) + next-iter F/off/mix +
//    colsum reset.  grid (BB, 8).
// ---------------------------------------------------------------------------
__global__ __launch_bounds__(256) void fprep_fused_kernel(
    const float* __restrict__ s1p, const float* __restrict__ s2p,
    const float* __restrict__ queries, float* __restrict__ colsum,
    short* __restrict__ F_bt, float* __restrict__ off, float* __restrict__ mix16)
{
    int b = blockIdx.x, k = blockIdx.y;
    int tid = threadIdx.x;
    float cs   = colsum[b * KK + k];
    float inv  = 1.0f / (cs + EPS_);
    float ssum = cs * inv;
    short* Fr = F_bt + (size_t)(b * 16 + k) * 1024;

    float c = 0.0f, ld = 0.0f;
#pragma unroll
    for (int q = 0; q < 2; q++) {
        int d = tid * 2 + q;
        float s1 = 0.0f, s2 = 0.0f;
#pragma unroll
        for (int ns = 0; ns < 16; ns++) {
            size_t o = ((size_t)(b * 16 + ns) * KK + k) * DD + d;
            s1 += s1p[o];
            s2 += s2p[o];
        }
        float m  = s1 * inv;
        float sg = s2 * inv - m * m * (2.0f - ssum);
        float iv = 1.0f / (sg * sg + EPS_);
        float qv = queries[((size_t)(b * KK + k)) * DD + d];
        Fr[d]       = f2bf(-0.5f * iv);
        Fr[512 + d] = f2bf(qv * iv);
        c  = fmaf(qv * qv, iv, c);
        ld += logf(fabsf(sg) + EPS_);
    }
    __shared__ float rc[256], rl[256];
    rc[tid] = c; rl[tid] = ld;
    __syncthreads();
    for (int s = 128; s > 0; s >>= 1) {
        if (tid < s) { rc[tid] += rc[tid + s]; rl[tid] += rl[tid + s]; }
        __syncthreads();
    }
    if (tid == 0) {
        off[b * 16 + k]    = GLL_C0 - 0.5f * rl[0] - 0.5f * rc[0];
        mix16[b * 16 + k]  = ssum * (1.0f / NN);
        colsum[b * KK + k] = 0.0f;
    }
}

// ---------------------------------------------------------------------------
// 7) Final: finalize last iter (mu/sigma from partials) -> slots out; attn^T.
// ---------------------------------------------------------------------------
__global__ __launch_bounds__(256) void final_kernel(
    const float* __restrict__ s1p, const float* __restrict__ s2p,
    const float* __restrict__ colsum, const float* __restrict__ noise_final,
    const float* __restrict__ attn, float* __restrict__ out)
{
    int gid = blockIdx.x * 256 + threadIdx.x;
    if (gid < BB * KK * DD) {
        int d = gid & 511;
        int k = (gid >> 9) & 7;
        int b = gid >> 12;
        float s1 = 0.0f, s2 = 0.0f;
#pragma unroll
        for (int ns = 0; ns < 16; ns++) {
            size_t o = ((size_t)(b * 16 + ns) * KK + k) * DD + d;
            s1 += s1p[o];
            s2 += s2p[o];
        }
        float cs   = colsum[b * KK + k];
        float inv  = 1.0f / (cs + EPS_);
        float ssum = cs * inv;
        float m    = s1 * inv;
        float sg   = s2 * inv - m * m * (2.0f - ssum);
        out[gid] = fmaf(fmaxf(fabsf(sg), EPS_), noise_final[gid], m);
    }
    if (gid < BB * KK * NN) {
        int b = gid >> 13;
        int k = (gid >> 10) & 7;
        int n = gid & 1023;
        float cs = colsum[b * KK + k];
        out[BB * KK * DD + gid] = attn[((size_t)(b * NN + n)) * KK + k] / (cs + EPS_);
    }
}

// ---------------------------------------------------------------------------
extern "C" void kernel_launch(void* const* d_in, const int* in_sizes, int n_in,
                              void* d_out, int out_size, void* d_ws, size_t ws_size,
                              hipStream_t stream)
{
    const float* emb         = (const float*)d_in[0];
    const float* noise_init  = (const float*)d_in[1];
    const float* noise_final = (const float*)d_in[2];
    const float* slots_mu    = (const float*)d_in[3];
    const float* slots_logsg = (const float*)d_in[4];
    const float* mixing_co   = (const float*)d_in[5];
    const float* Wk          = (const float*)d_in[6];
    const float* bk          = (const float*)d_in[7];
    const float* Wq          = (const float*)d_in[8];
    const float* bq          = (const float*)d_in[9];
    const float* Wv          = (const float*)d_in[10];
    const float* bv          = (const float*)d_in[11];
    const float* ln_g        = (const float*)d_in[12];
    const float* ln_b        = (const float*)d_in[13];
    float* out = (float*)d_out;

    // workspace layout
    float* ws = (float*)d_ws;
    float* queries = ws;                                 // 65536
    float* attn    = queries + BB * KK * DD;             // 131072
    float* s1p     = attn + BB * NN * KK;                // 16*16*8*512 = 1048576
    float* s2p     = s1p + (size_t)BB * 16 * KK * DD;    // 1048576
    float* off     = s2p + (size_t)BB * 16 * KK * DD;    // 256
    float* mix16   = off + BB * 16;                      // 256
    float* colsum  = mix16 + BB * 16;                    // 128
    short* Abf     = (short*)(colsum + BB * KK);         // 16*1024*512
    short* E       = Abf + (size_t)BB * NN * DD;         // 16*1024*1024
    short* Vbf     = E + (size_t)BB * NN * 1024;         // 16*1024*512
    short* WtKV    = Vbf + (size_t)BB * NN * DD;         // 1024*512
    short* WqT     = WtKV + (size_t)1024 * DD;           // 512*512
    short* slotbf  = WqT + (size_t)DD * DD;              // 128*512
    short* F_bt    = slotbf + (size_t)BB * KK * DD;      // 16*16*1024

    pre_kernel<<<4992, 256, 0, stream>>>(
        emb, ln_g, ln_b, Abf, Wk, Wv, Wq, WtKV, WqT,
        noise_init, slots_mu, slots_logsg, slotbf);

    // keys -> E, values -> Vbf, queries -> fp32 (one merged N=1024 dispatch)
    gemm_mfma_kernel<<<dim3(8, 129), 256, 0, stream>>>(
        Abf, slotbf, WtKV, WqT, bk, bv, bq, E, Vbf, queries);

    fprep0_kernel<<<dim3(BB, 16), 256, 0, stream>>>(
        slots_logsg, queries, mixing_co, F_bt, off, mix16, colsum);

    for (int it = 0; it < 3; it++) {
        gll_mfma_kernel<<<dim3(64, BB), 256, 0, stream>>>(
            E, F_bt, off, mix16, attn, colsum);
        musigma_kernel<<<dim3(BB, 16), 256, 0, stream>>>(Vbf, attn, s1p, s2p);
        if (it < 2)
            fprep_fused_kernel<<<dim3(BB, KK), 256, 0, stream>>>(
                s1p, s2p, queries, colsum, F_bt, off, mix16);
    }

    final_kernel<<<BB * KK * NN / 256, 256, 0, stream>>>(
        s1p, s2p, colsum, noise_final, attn, out);
}